// Round 2
// baseline (609.500 us; speedup 1.0000x reference)
//
#include <hip/hip_runtime.h>
#include <hip/hip_bf16.h>
#include <stdint.h>

#define B_  2
#define S_  4096
#define D_  1024
#define FF_ 4096
#define E_  8
#define C_  1024

typedef unsigned short u16;
typedef unsigned int   u32;
typedef float f32x4  __attribute__((ext_vector_type(4)));
typedef short bf16x8 __attribute__((ext_vector_type(8)));
typedef u16   u16x8  __attribute__((ext_vector_type(8)));

static __device__ __forceinline__ u16 f2bf(float f) {
    union { float f; u32 u; } v; v.f = f;
    u32 u = v.u;
    u32 r = (u + 0x7FFFu + ((u >> 16) & 1u)) >> 16;  // RNE; inputs are finite
    return (u16)r;
}

static __device__ __forceinline__ void gload_lds16(const u16* g, u16* l) {
    __builtin_amdgcn_global_load_lds(
        (const __attribute__((address_space(1))) u32*)g,
        (__attribute__((address_space(3))) u32*)l, 16, 0, 0);
}

#define BAR()    asm volatile("s_barrier" ::: "memory")
#define WAITV(n) asm volatile("s_waitcnt vmcnt(" #n ")" ::: "memory")

// ============ transpose + convert: [K][N] fp32 -> [N][K] bf16, per expert ============
// 64(n) x 64(k) tile. LDS row n = 128B, 8 slots of 16B; phys slot = (k>>3) ^ swz(n),
// swz(n) = (n&7)^((n>>3)&7)  (mixes enough n bits for conflict-free stores).
__global__ __launch_bounds__(256) void transpose_cvt(const float* __restrict__ src,
                                                     u16* __restrict__ dst, int K, int N) {
    __shared__ u16 t[64 * 64];
    size_t mat = (size_t)blockIdx.z * K * N;
    int n0 = blockIdx.x * 64, k0 = blockIdx.y * 64;
    int l = threadIdx.x & 63, w = threadIdx.x >> 6;
#pragma unroll
    for (int p = 0; p < 2; ++p) {
        int k = p * 32 + w * 8 + ((l >> 4) << 1);     // even k
        int n = (l & 15) * 4;
        float4 v0 = *(const float4*)&src[mat + (size_t)(k0 + k) * N + n0 + n];
        float4 v1 = *(const float4*)&src[mat + (size_t)(k0 + k + 1) * N + n0 + n];
        float a0[4] = {v0.x, v0.y, v0.z, v0.w};
        float a1[4] = {v1.x, v1.y, v1.z, v1.w};
#pragma unroll
        for (int j = 0; j < 4; ++j) {
            int nn = n + j;
            u32 pk = (u32)f2bf(a0[j]) | ((u32)f2bf(a1[j]) << 16);
            int slot = (k >> 3) ^ ((nn & 7) ^ ((nn >> 3) & 7));
            *(u32*)((char*)t + nn * 128 + slot * 16 + (k & 7) * 2) = pk;
        }
    }
    __syncthreads();
#pragma unroll
    for (int p = 0; p < 2; ++p) {
        int n = p * 32 + (threadIdx.x >> 3);
        int k8 = threadIdx.x & 7;
        int slot = k8 ^ ((n & 7) ^ ((n >> 3) & 7));
        u16x8 v = *(u16x8*)((char*)t + n * 128 + slot * 16);
        *(u16x8*)&dst[mat + (size_t)(n0 + n) * K + k0 + k8 * 8] = v;
    }
}

// ============ router: logits (fp64 accum), argmax, max softmax prob; fused bf16 cvt ============
__global__ __launch_bounds__(256) void router_kernel(const float* __restrict__ hidden,
                                                     const float* __restrict__ gate_w,
                                                     float* __restrict__ logits_out,
                                                     int* __restrict__ sel,
                                                     float* __restrict__ maxp,
                                                     u16* __restrict__ xbf) {
    __shared__ float gw[D_ * E_];   // 32 KB
    for (int i = threadIdx.x; i < D_ * E_ / 4; i += 256)
        ((float4*)gw)[i] = ((const float4*)gate_w)[i];
    __syncthreads();

    int wave = threadIdx.x >> 6, lane = threadIdx.x & 63;
    int tok = blockIdx.x * 4 + wave;              // [0, B*S)
    const float* hrow = hidden + (size_t)tok * D_;
    u16* xrow = xbf + (size_t)tok * D_;

    double acc[8] = {0, 0, 0, 0, 0, 0, 0, 0};
#pragma unroll 4
    for (int i = 0; i < D_ / 64; i++) {
        int d = i * 64 + lane;
        float h = hrow[d];
        xrow[d] = f2bf(h);
        const float4* g4 = (const float4*)(gw + d * 8);
        float4 g0 = g4[0], g1 = g4[1];
        acc[0] += (double)h * g0.x; acc[1] += (double)h * g0.y;
        acc[2] += (double)h * g0.z; acc[3] += (double)h * g0.w;
        acc[4] += (double)h * g1.x; acc[5] += (double)h * g1.y;
        acc[6] += (double)h * g1.z; acc[7] += (double)h * g1.w;
    }
#pragma unroll
    for (int off = 32; off > 0; off >>= 1)
#pragma unroll
        for (int e = 0; e < 8; e++)
            acc[e] += __shfl_xor(acc[e], off);

    float l[8];
#pragma unroll
    for (int e = 0; e < 8; e++) l[e] = (float)acc[e];
    if (lane < 8) logits_out[(size_t)tok * 8 + lane] = l[lane];

    int am = 0; float mx = l[0];
#pragma unroll
    for (int e = 1; e < 8; e++) if (l[e] > mx) { mx = l[e]; am = e; }
    float sum = 0.f;
#pragma unroll
    for (int e = 0; e < 8; e++) sum += expf(l[e] - mx);
    if (lane == 0) { sel[tok] = am; maxp[tok] = 1.0f / sum; }
}

// ============ routing scan: per-(batch,expert) rank via wave ballots ============
__global__ void scan_kernel(const int* __restrict__ sel, int* __restrict__ pos,
                            int* __restrict__ slot_token, int* __restrict__ counts) {
    int wave = threadIdx.x >> 6, lane = threadIdx.x & 63;
    int b = wave;
    int carry[8] = {0, 0, 0, 0, 0, 0, 0, 0};
    unsigned long long below = (lane == 0) ? 0ull : ((~0ull) >> (64 - lane));
    for (int s0 = 0; s0 < S_; s0 += 64) {
        int s = s0 + lane;
        int e = sel[b * S_ + s];
        int p = 0;
#pragma unroll
        for (int ex = 0; ex < 8; ex++) {
            unsigned long long m = __ballot(e == ex);
            if (e == ex) p = carry[ex] + (int)__popcll(m & below);
            carry[ex] += (int)__popcll(m);
        }
        pos[b * S_ + s] = p;
        if (p < C_) slot_token[(b * E_ + e) * C_ + p] = s;
    }
    if (lane < 8) {
        int c = carry[lane];
        counts[b * E_ + lane] = c < C_ ? c : C_;
    }
}

// ============ GEMM1: h = silu(x@w1) * (x@w3) ============
// tile 128(slots) x 128(ff) dual-panel, BK=32, 4 waves (2x2), wave 64x64 per panel.
// LDS/buf: A 8K | B1 8K | B3 8K; dbuf 48 KB. Row-pair swizzle: rp=row>>1, 8 slots/128B,
// phys slot = natural ^ (rp&7); natural ss: row=2rp+(ss>>2), k-chunk=(ss&3)*8.
__global__ __launch_bounds__(256) void gemm1_kernel(const u16* __restrict__ x,
                                                    const u16* __restrict__ w1t,
                                                    const u16* __restrict__ w3t,
                                                    const int* __restrict__ slot_token,
                                                    const int* __restrict__ counts,
                                                    u16* __restrict__ hbuf) {
    int z = blockIdx.z;
    int cnt = counts[z];
    int c0 = blockIdx.y * 128;
    if (c0 >= cnt) return;
    int n0 = blockIdx.x * 128;
    int b = z >> 3, e = z & 7;

    __shared__ u16 lds[2 * 12288];

    int tid = threadIdx.x, w = tid >> 6, l = tid & 63;
    int wr = w >> 1, wc = w & 1;

    const u16 *aptr[2], *b1ptr[2], *b3ptr[2];
    int sbase[2];
#pragma unroll
    for (int i = 0; i < 2; i++) {
        int rp = w * 16 + i * 8 + (l >> 3);
        int ss = (l & 7) ^ (rp & 7);
        int r  = 2 * rp + (ss >> 2);
        int ko = (ss & 3) * 8;
        int slot = c0 + r;
        int tok = (slot < cnt) ? slot_token[z * C_ + slot] : 0;
        aptr[i]  = x   + (size_t)(b * S_ + tok) * D_ + ko;
        b1ptr[i] = w1t + ((size_t)e * FF_ + n0 + r) * D_ + ko;
        b3ptr[i] = w3t + ((size_t)e * FF_ + n0 + r) * D_ + ko;
        sbase[i] = (w * 16 + i * 8) * 64;
    }

    int afo[4], bfo[4];
#pragma unroll
    for (int f = 0; f < 4; f++) {
        int rA = wr * 64 + f * 16 + (l & 15);
        int rp = rA >> 1;
        int ss = (rA & 1) * 4 + (l >> 4);
        afo[f] = rp * 64 + (ss ^ (rp & 7)) * 8;
        int nl = wc * 64 + f * 16 + (l & 15);
        int rpb = nl >> 1;
        int ssb = (nl & 1) * 4 + (l >> 4);
        bfo[f] = rpb * 64 + (ssb ^ (rpb & 7)) * 8;
    }

    f32x4 acc1[4][4] = {};
    f32x4 acc3[4][4] = {};

    auto STAGE = [&](int buf, int t) {
        u16* Ld = lds + buf * 12288;
        int k0 = t * 32;
#pragma unroll
        for (int i = 0; i < 2; i++) {
            gload_lds16(aptr[i]  + k0, Ld + sbase[i]);
            gload_lds16(b1ptr[i] + k0, Ld + 4096 + sbase[i]);
            gload_lds16(b3ptr[i] + k0, Ld + 8192 + sbase[i]);
        }
    };

    constexpr int NT = D_ / 32;  // 32
    STAGE(0, 0);
    for (int t = 0; t < NT; ++t) {
        int cur = t & 1;
        if (t + 1 < NT) {
            STAGE(cur ^ 1, t + 1);
            WAITV(6);
        } else {
            WAITV(0);
        }
        BAR();
        const u16* Lc = lds + cur * 12288;
        bf16x8 af[4], b1f[4], b3f[4];
#pragma unroll
        for (int f = 0; f < 4; f++) af[f]  = *(const bf16x8*)(Lc + afo[f]);
#pragma unroll
        for (int f = 0; f < 4; f++) b1f[f] = *(const bf16x8*)(Lc + 4096 + bfo[f]);
#pragma unroll
        for (int f = 0; f < 4; f++) b3f[f] = *(const bf16x8*)(Lc + 8192 + bfo[f]);
        __builtin_amdgcn_s_setprio(1);
#pragma unroll
        for (int fm = 0; fm < 4; fm++)
#pragma unroll
            for (int fn = 0; fn < 4; fn++) {
                acc1[fm][fn] = __builtin_amdgcn_mfma_f32_16x16x32_bf16(af[fm], b1f[fn], acc1[fm][fn], 0, 0, 0);
                acc3[fm][fn] = __builtin_amdgcn_mfma_f32_16x16x32_bf16(af[fm], b3f[fn], acc3[fm][fn], 0, 0, 0);
            }
        __builtin_amdgcn_s_setprio(0);
        BAR();
    }

#pragma unroll
    for (int fm = 0; fm < 4; fm++) {
        int rb = c0 + wr * 64 + fm * 16 + ((l >> 4) << 2);
#pragma unroll
        for (int fn = 0; fn < 4; fn++) {
            int col = n0 + wc * 64 + fn * 16 + (l & 15);
#pragma unroll
            for (int r = 0; r < 4; r++) {
                int slot = rb + r;
                if (slot < cnt) {
                    float g = acc1[fm][fn][r], u = acc3[fm][fn][r];
                    float h = (g / (1.f + __expf(-g))) * u;
                    hbuf[((size_t)z * C_ + slot) * FF_ + col] = f2bf(h);
                }
            }
        }
    }
}

// ============ GEMM2: out[token] = maxp * (h @ w2), scatter epilogue ============
// tile 128(slots) x 128(d), BK=32, 4 waves (2x2), wave 64x64. LDS/buf: A 8K | B 8K; dbuf 32 KB.
__global__ __launch_bounds__(256) void gemm2_kernel(const u16* __restrict__ hbuf,
                                                    const u16* __restrict__ w2t,
                                                    const int* __restrict__ slot_token,
                                                    const int* __restrict__ counts,
                                                    const float* __restrict__ maxp,
                                                    float* __restrict__ out) {
    int z = blockIdx.z;
    int cnt = counts[z];
    int c0 = blockIdx.y * 128;
    if (c0 >= cnt) return;
    int n0 = blockIdx.x * 128;
    int b = z >> 3, e = z & 7;

    __shared__ u16 lds[2 * 8192];

    int tid = threadIdx.x, w = tid >> 6, l = tid & 63;
    int wr = w >> 1, wc = w & 1;

    const u16 *aptr[2], *bptr[2];
    int sbase[2];
#pragma unroll
    for (int i = 0; i < 2; i++) {
        int rp = w * 16 + i * 8 + (l >> 3);
        int ss = (l & 7) ^ (rp & 7);
        int r  = 2 * rp + (ss >> 2);
        int ko = (ss & 3) * 8;
        aptr[i] = hbuf + ((size_t)z * C_ + c0 + r) * FF_ + ko;
        bptr[i] = w2t + ((size_t)e * D_ + n0 + r) * FF_ + ko;
        sbase[i] = (w * 16 + i * 8) * 64;
    }

    int afo[4], bfo[4];
#pragma unroll
    for (int f = 0; f < 4; f++) {
        int rA = wr * 64 + f * 16 + (l & 15);
        int rp = rA >> 1;
        int ss = (rA & 1) * 4 + (l >> 4);
        afo[f] = rp * 64 + (ss ^ (rp & 7)) * 8;
        int nl = wc * 64 + f * 16 + (l & 15);
        int rpb = nl >> 1;
        int ssb = (nl & 1) * 4 + (l >> 4);
        bfo[f] = rpb * 64 + (ssb ^ (rpb & 7)) * 8;
    }

    f32x4 acc[4][4] = {};

    auto STAGE = [&](int buf, int t) {
        u16* Ld = lds + buf * 8192;
        int k0 = t * 32;
#pragma unroll
        for (int i = 0; i < 2; i++) {
            gload_lds16(aptr[i] + k0, Ld + sbase[i]);
            gload_lds16(bptr[i] + k0, Ld + 4096 + sbase[i]);
        }
    };

    constexpr int NT = FF_ / 32;  // 128
    STAGE(0, 0);
    for (int t = 0; t < NT; ++t) {
        int cur = t & 1;
        if (t + 1 < NT) {
            STAGE(cur ^ 1, t + 1);
            WAITV(4);
        } else {
            WAITV(0);
        }
        BAR();
        const u16* Lc = lds + cur * 8192;
        bf16x8 af[4], bfv[4];
#pragma unroll
        for (int f = 0; f < 4; f++) af[f]  = *(const bf16x8*)(Lc + afo[f]);
#pragma unroll
        for (int f = 0; f < 4; f++) bfv[f] = *(const bf16x8*)(Lc + 4096 + bfo[f]);
        __builtin_amdgcn_s_setprio(1);
#pragma unroll
        for (int fm = 0; fm < 4; fm++)
#pragma unroll
            for (int fn = 0; fn < 4; fn++)
                acc[fm][fn] = __builtin_amdgcn_mfma_f32_16x16x32_bf16(af[fm], bfv[fn], acc[fm][fn], 0, 0, 0);
        __builtin_amdgcn_s_setprio(0);
        BAR();
    }

#pragma unroll
    for (int fm = 0; fm < 4; fm++) {
        int rb = c0 + wr * 64 + fm * 16 + ((l >> 4) << 2);
#pragma unroll
        for (int r = 0; r < 4; r++) {
            int slot = rb + r;
            if (slot < cnt) {
                int s = slot_token[z * C_ + slot];
                float sc = maxp[b * S_ + s];
                float* orow = out + ((size_t)b * S_ + s) * D_;
#pragma unroll
                for (int fn = 0; fn < 4; fn++) {
                    int col = n0 + wc * 64 + fn * 16 + (l & 15);
                    orow[col] = sc * acc[fm][fn][r];
                }
            }
        }
    }
}

// ============ dropped tokens keep hidden (rare; usually no-op) ============
__global__ __launch_bounds__(256) void combine_dropped(const float* __restrict__ hidden,
                                                       const int* __restrict__ pos,
                                                       const float* __restrict__ maxp,
                                                       float* __restrict__ out) {
    int t = blockIdx.x;
    if (pos[t] < C_) return;
    float sc = maxp[t];
    const float* src = hidden + (size_t)t * D_;
    float* dst = out + (size_t)t * D_;
    for (int d = threadIdx.x; d < D_; d += 256) dst[d] = sc * src[d];
}

extern "C" void kernel_launch(void* const* d_in, const int* in_sizes, int n_in,
                              void* d_out, int out_size, void* d_ws, size_t ws_size,
                              hipStream_t stream) {
    const float* hidden = (const float*)d_in[0];
    const float* gate_w = (const float*)d_in[1];
    const float* w1     = (const float*)d_in[2];
    const float* w2     = (const float*)d_in[3];
    const float* w3     = (const float*)d_in[4];

    float* out        = (float*)d_out;
    float* logits_out = out + (size_t)B_ * S_ * D_;

    char* ws = (char*)d_ws;
    u16* hidden_bf = (u16*)ws;            ws += (size_t)B_ * S_ * D_ * 2;
    u16* w1t       = (u16*)ws;            ws += (size_t)E_ * D_ * FF_ * 2;
    u16* w3t       = (u16*)ws;            ws += (size_t)E_ * D_ * FF_ * 2;
    u16* w2t       = (u16*)ws;            ws += (size_t)E_ * D_ * FF_ * 2;
    u16* hbuf      = (u16*)ws;            ws += (size_t)B_ * E_ * C_ * FF_ * 2;
    int*   sel        = (int*)ws;         ws += (size_t)B_ * S_ * 4;
    int*   pos        = (int*)ws;         ws += (size_t)B_ * S_ * 4;
    float* maxp       = (float*)ws;       ws += (size_t)B_ * S_ * 4;
    int*   slot_token = (int*)ws;         ws += (size_t)B_ * E_ * C_ * 4;
    int*   counts     = (int*)ws;         ws += (size_t)B_ * E_ * 4;

    router_kernel<<<B_ * S_ / 4, 256, 0, stream>>>(hidden, gate_w, logits_out, sel, maxp, hidden_bf);
    scan_kernel<<<1, 128, 0, stream>>>(sel, pos, slot_token, counts);

    transpose_cvt<<<dim3(FF_ / 64, D_ / 64, E_), 256, 0, stream>>>(w1, w1t, D_, FF_);
    transpose_cvt<<<dim3(FF_ / 64, D_ / 64, E_), 256, 0, stream>>>(w3, w3t, D_, FF_);
    transpose_cvt<<<dim3(D_ / 64, FF_ / 64, E_), 256, 0, stream>>>(w2, w2t, FF_, D_);

    gemm1_kernel<<<dim3(FF_ / 128, C_ / 128, B_ * E_), 256, 0, stream>>>(hidden_bf, w1t, w3t, slot_token, counts, hbuf);
    gemm2_kernel<<<dim3(D_ / 128, C_ / 128, B_ * E_), 256, 0, stream>>>(hbuf, w2t, slot_token, counts, maxp, out);
    combine_dropped<<<B_ * S_, 256, 0, stream>>>(hidden, pos, maxp, out);
}

// Round 3
// 517.335 us; speedup vs baseline: 1.1782x; 1.1782x over previous
//
#include <hip/hip_runtime.h>
#include <hip/hip_bf16.h>
#include <stdint.h>

#define B_  2
#define S_  4096
#define D_  1024
#define FF_ 4096
#define E_  8
#define C_  1024

typedef unsigned short u16;
typedef unsigned int   u32;
typedef float f32x4  __attribute__((ext_vector_type(4)));
typedef short bf16x8 __attribute__((ext_vector_type(8)));
typedef u16   u16x8  __attribute__((ext_vector_type(8)));

static __device__ __forceinline__ u16 f2bf(float f) {
    union { float f; u32 u; } v; v.f = f;
    u32 u = v.u;
    u32 r = (u + 0x7FFFu + ((u >> 16) & 1u)) >> 16;  // RNE; inputs are finite
    return (u16)r;
}

static __device__ __forceinline__ void gload_lds16(const u16* g, u16* l) {
    __builtin_amdgcn_global_load_lds(
        (const __attribute__((address_space(1))) u32*)g,
        (__attribute__((address_space(3))) u32*)l, 16, 0, 0);
}

#define BAR()    asm volatile("s_barrier" ::: "memory")
#define WAITV(n) asm volatile("s_waitcnt vmcnt(" #n ")" ::: "memory")

// ============ transpose + convert: [K][N] fp32 -> [N][K] bf16, per expert ============
__global__ __launch_bounds__(256) void transpose_cvt(const float* __restrict__ src,
                                                     u16* __restrict__ dst, int K, int N) {
    __shared__ u16 t[64 * 64];
    size_t mat = (size_t)blockIdx.z * K * N;
    int n0 = blockIdx.x * 64, k0 = blockIdx.y * 64;
    int l = threadIdx.x & 63, w = threadIdx.x >> 6;
#pragma unroll
    for (int p = 0; p < 2; ++p) {
        int k = p * 32 + w * 8 + ((l >> 4) << 1);     // even k
        int n = (l & 15) * 4;
        float4 v0 = *(const float4*)&src[mat + (size_t)(k0 + k) * N + n0 + n];
        float4 v1 = *(const float4*)&src[mat + (size_t)(k0 + k + 1) * N + n0 + n];
        float a0[4] = {v0.x, v0.y, v0.z, v0.w};
        float a1[4] = {v1.x, v1.y, v1.z, v1.w};
#pragma unroll
        for (int j = 0; j < 4; ++j) {
            int nn = n + j;
            u32 pk = (u32)f2bf(a0[j]) | ((u32)f2bf(a1[j]) << 16);
            int slot = (k >> 3) ^ ((nn & 7) ^ ((nn >> 3) & 7));
            *(u32*)((char*)t + nn * 128 + slot * 16 + (k & 7) * 2) = pk;
        }
    }
    __syncthreads();
#pragma unroll
    for (int p = 0; p < 2; ++p) {
        int n = p * 32 + (threadIdx.x >> 3);
        int k8 = threadIdx.x & 7;
        int slot = k8 ^ ((n & 7) ^ ((n >> 3) & 7));
        u16x8 v = *(u16x8*)((char*)t + n * 128 + slot * 16);
        *(u16x8*)&dst[mat + (size_t)(n0 + n) * K + k0 + k8 * 8] = v;
    }
}

// ============ router: logits (fp64 accum), argmax, max softmax prob; fused bf16 cvt ============
__global__ __launch_bounds__(256) void router_kernel(const float* __restrict__ hidden,
                                                     const float* __restrict__ gate_w,
                                                     float* __restrict__ logits_out,
                                                     int* __restrict__ sel,
                                                     float* __restrict__ maxp,
                                                     u16* __restrict__ xbf) {
    __shared__ float gw[D_ * E_];   // 32 KB
    for (int i = threadIdx.x; i < D_ * E_ / 4; i += 256)
        ((float4*)gw)[i] = ((const float4*)gate_w)[i];
    __syncthreads();

    int wave = threadIdx.x >> 6, lane = threadIdx.x & 63;
    int tok = blockIdx.x * 4 + wave;              // [0, B*S)
    const float* hrow = hidden + (size_t)tok * D_;
    u16* xrow = xbf + (size_t)tok * D_;

    double acc[8] = {0, 0, 0, 0, 0, 0, 0, 0};
#pragma unroll 4
    for (int i = 0; i < D_ / 64; i++) {
        int d = i * 64 + lane;
        float h = hrow[d];
        xrow[d] = f2bf(h);
        const float4* g4 = (const float4*)(gw + d * 8);
        float4 g0 = g4[0], g1 = g4[1];
        acc[0] += (double)h * g0.x; acc[1] += (double)h * g0.y;
        acc[2] += (double)h * g0.z; acc[3] += (double)h * g0.w;
        acc[4] += (double)h * g1.x; acc[5] += (double)h * g1.y;
        acc[6] += (double)h * g1.z; acc[7] += (double)h * g1.w;
    }
#pragma unroll
    for (int off = 32; off > 0; off >>= 1)
#pragma unroll
        for (int e = 0; e < 8; e++)
            acc[e] += __shfl_xor(acc[e], off);

    float l[8];
#pragma unroll
    for (int e = 0; e < 8; e++) l[e] = (float)acc[e];
    if (lane < 8) logits_out[(size_t)tok * 8 + lane] = l[lane];

    int am = 0; float mx = l[0];
#pragma unroll
    for (int e = 1; e < 8; e++) if (l[e] > mx) { mx = l[e]; am = e; }
    float sum = 0.f;
#pragma unroll
    for (int e = 0; e < 8; e++) sum += expf(l[e] - mx);
    if (lane == 0) { sel[tok] = am; maxp[tok] = 1.0f / sum; }
}

// ============ routing scan: per-(batch,expert) rank via wave ballots ============
__global__ void scan_kernel(const int* __restrict__ sel, int* __restrict__ pos,
                            int* __restrict__ slot_token, int* __restrict__ counts) {
    int wave = threadIdx.x >> 6, lane = threadIdx.x & 63;
    int b = wave;
    int carry[8] = {0, 0, 0, 0, 0, 0, 0, 0};
    unsigned long long below = (lane == 0) ? 0ull : ((~0ull) >> (64 - lane));
    for (int s0 = 0; s0 < S_; s0 += 64) {
        int s = s0 + lane;
        int e = sel[b * S_ + s];
        int p = 0;
#pragma unroll
        for (int ex = 0; ex < 8; ex++) {
            unsigned long long m = __ballot(e == ex);
            if (e == ex) p = carry[ex] + (int)__popcll(m & below);
            carry[ex] += (int)__popcll(m);
        }
        pos[b * S_ + s] = p;
        if (p < C_) slot_token[(b * E_ + e) * C_ + p] = s;
    }
    if (lane < 8) {
        int c = carry[lane];
        counts[b * E_ + lane] = c < C_ ? c : C_;
    }
}

// ============ GEMM1: h = silu(x@w1) * (x@w3) ============
// tile 256(M slots) x 128(N per panel, w1 & w3 share A). K-phase=32, 4-slot LDS rotation
// (slot = 32KB: A 256x32 | B1 128x32 | B3 128x32), prefetch depth 3, 8 waves (2M x 4N).
// Per phase/wave: 12 ds_read_b128, 32 MFMA; stage = 4 global_load_lds(16B)/thread.
__global__ __launch_bounds__(512, 2) void gemm1_kernel(const u16* __restrict__ x,
                                                       const u16* __restrict__ w1t,
                                                       const u16* __restrict__ w3t,
                                                       const int* __restrict__ slot_token,
                                                       const int* __restrict__ counts,
                                                       u16* __restrict__ hbuf) {
    extern __shared__ u16 lds[];   // 4 * 16384 u16 = 128 KB
    // bijective XCD chunk swizzle (nwg = 2048, q = 256)
    int phys = blockIdx.x + 32 * (blockIdx.y + 4 * blockIdx.z);
    int virt = (phys & 7) * 256 + (phys >> 3);
    int bx = virt & 31, by = (virt >> 5) & 3, bz = virt >> 7;

    int z = bz;
    int cnt = counts[z];
    int c0 = by * 256;
    if (c0 >= cnt) return;
    int n0 = bx * 128;
    int b = z >> 3, e = z & 7;

    int tid = threadIdx.x, w = tid >> 6, l = tid & 63;
    int wm = w >> 2, wn = w & 3;

    // staging sources (per-lane); dest is linear per wave slice
    int arow0 = tid >> 2, arow1 = arow0 + 128;
    int as0 = c0 + arow0, as1 = c0 + arow1;
    int tok0 = slot_token[z * C_ + (as0 < cnt ? as0 : 0)];
    int tok1 = slot_token[z * C_ + (as1 < cnt ? as1 : 0)];
    const u16* pA0 = x + ((size_t)(b * S_ + tok0)) * D_ + (tid & 3) * 8;
    const u16* pA1 = x + ((size_t)(b * S_ + tok1)) * D_ + (tid & 3) * 8;
    const u16* pB1 = w1t + ((size_t)e * FF_ + n0 + arow0) * D_ + (tid & 3) * 8;
    const u16* pB3 = w3t + ((size_t)e * FF_ + n0 + arow0) * D_ + (tid & 3) * 8;
    u32 wsl = (u32)w * 512;

    // fragment read offsets (u16 units within slot)
    u32 aoff  = (u32)(wm * 128 + (l & 15)) * 32 + (l >> 4) * 8;           // + f*512
    u32 b1off = 8192  + (u32)(wn * 32 + (l & 15)) * 32 + (l >> 4) * 8;    // + n*512
    u32 b3off = 12288 + (u32)(wn * 32 + (l & 15)) * 32 + (l >> 4) * 8;

    auto STAGE = [&](int t) {
        u16* Ls = lds + ((t & 3) << 14);
        int ko = t << 5;
        gload_lds16(pA0 + ko, Ls + wsl);
        gload_lds16(pA1 + ko, Ls + 4096 + wsl);
        gload_lds16(pB1 + ko, Ls + 8192 + wsl);
        gload_lds16(pB3 + ko, Ls + 12288 + wsl);
    };

    f32x4 acc1[8][2] = {};
    f32x4 acc3[8][2] = {};

    constexpr int NK = D_ / 32;  // 32
    STAGE(0); STAGE(1); STAGE(2);
    for (int t = 0; t < NK; ++t) {
        if (t + 2 < NK)      { WAITV(8); }
        else if (t + 1 < NK) { WAITV(4); }
        else                 { WAITV(0); }
        BAR();
        if (t + 3 < NK) STAGE(t + 3);
        const u16* Ls = lds + ((t & 3) << 14);
        bf16x8 af[8], b1f[2], b3f[2];
#pragma unroll
        for (int f = 0; f < 8; f++) af[f] = *(const bf16x8*)(Ls + aoff + f * 512);
#pragma unroll
        for (int n = 0; n < 2; n++) {
            b1f[n] = *(const bf16x8*)(Ls + b1off + n * 512);
            b3f[n] = *(const bf16x8*)(Ls + b3off + n * 512);
        }
        __builtin_amdgcn_s_setprio(1);
#pragma unroll
        for (int f = 0; f < 8; f++)
#pragma unroll
            for (int n = 0; n < 2; n++) {
                acc1[f][n] = __builtin_amdgcn_mfma_f32_16x16x32_bf16(af[f], b1f[n], acc1[f][n], 0, 0, 0);
                acc3[f][n] = __builtin_amdgcn_mfma_f32_16x16x32_bf16(af[f], b3f[n], acc3[f][n], 0, 0, 0);
            }
        __builtin_amdgcn_s_setprio(0);
    }

#pragma unroll
    for (int f = 0; f < 8; f++) {
        int row = wm * 128 + f * 16 + ((l >> 4) << 2);
#pragma unroll
        for (int r = 0; r < 4; r++) {
            int slot = c0 + row + r;
            if (slot < cnt) {
                size_t base = ((size_t)z * C_ + slot) * FF_ + n0 + wn * 32 + (l & 15);
#pragma unroll
                for (int n = 0; n < 2; n++) {
                    float g = acc1[f][n][r], uu = acc3[f][n][r];
                    float h = (g / (1.f + __expf(-g))) * uu;
                    hbuf[base + n * 16] = f2bf(h);
                }
            }
        }
    }
}

// ============ GEMM2: out[token] = maxp * (h @ w2), scatter epilogue ============
// tile 256(M slots) x 256(N=d). K-phase=32, 4-slot rotation (slot = 32KB: A 256x32 | B 256x32),
// prefetch depth 3, 8 waves (2M x 4N), wave tile 128x64.
__global__ __launch_bounds__(512, 2) void gemm2_kernel(const u16* __restrict__ hbuf,
                                                       const u16* __restrict__ w2t,
                                                       const int* __restrict__ slot_token,
                                                       const int* __restrict__ counts,
                                                       const float* __restrict__ maxp,
                                                       float* __restrict__ out) {
    extern __shared__ u16 lds[];   // 128 KB
    // bijective XCD chunk swizzle (nwg = 256, q = 32)
    int phys = blockIdx.x + 4 * (blockIdx.y + 4 * blockIdx.z);
    int virt = (phys & 7) * 32 + (phys >> 3);
    int bx = virt & 3, by = (virt >> 2) & 3, bz = virt >> 4;

    int z = bz;
    int cnt = counts[z];
    int c0 = by * 256;
    if (c0 >= cnt) return;
    int n0 = bx * 256;
    int b = z >> 3, e = z & 7;

    int tid = threadIdx.x, w = tid >> 6, l = tid & 63;
    int wm = w >> 2, wn = w & 3;

    int arow0 = tid >> 2;
    const u16* pA0 = hbuf + ((size_t)z * C_ + c0 + arow0) * FF_ + (tid & 3) * 8;
    const u16* pA1 = pA0 + (size_t)128 * FF_;
    const u16* pB0 = w2t + ((size_t)e * D_ + n0 + arow0) * FF_ + (tid & 3) * 8;
    const u16* pB1 = pB0 + (size_t)128 * FF_;
    u32 wsl = (u32)w * 512;

    u32 aoff = (u32)(wm * 128 + (l & 15)) * 32 + (l >> 4) * 8;           // + f*512
    u32 boff = 8192 + (u32)(wn * 64 + (l & 15)) * 32 + (l >> 4) * 8;     // + n*512

    auto STAGE = [&](int t) {
        u16* Ls = lds + ((t & 3) << 14);
        int ko = t << 5;
        gload_lds16(pA0 + ko, Ls + wsl);
        gload_lds16(pA1 + ko, Ls + 4096 + wsl);
        gload_lds16(pB0 + ko, Ls + 8192 + wsl);
        gload_lds16(pB1 + ko, Ls + 12288 + wsl);
    };

    f32x4 acc[8][4] = {};

    constexpr int NK = FF_ / 32;  // 128
    STAGE(0); STAGE(1); STAGE(2);
    for (int t = 0; t < NK; ++t) {
        if (t + 2 < NK)      { WAITV(8); }
        else if (t + 1 < NK) { WAITV(4); }
        else                 { WAITV(0); }
        BAR();
        if (t + 3 < NK) STAGE(t + 3);
        const u16* Ls = lds + ((t & 3) << 14);
        bf16x8 af[8], bfv[4];
#pragma unroll
        for (int f = 0; f < 8; f++) af[f] = *(const bf16x8*)(Ls + aoff + f * 512);
#pragma unroll
        for (int n = 0; n < 4; n++) bfv[n] = *(const bf16x8*)(Ls + boff + n * 512);
        __builtin_amdgcn_s_setprio(1);
#pragma unroll
        for (int f = 0; f < 8; f++)
#pragma unroll
            for (int n = 0; n < 4; n++)
                acc[f][n] = __builtin_amdgcn_mfma_f32_16x16x32_bf16(af[f], bfv[n], acc[f][n], 0, 0, 0);
        __builtin_amdgcn_s_setprio(0);
    }

#pragma unroll
    for (int f = 0; f < 8; f++) {
        int row = wm * 128 + f * 16 + ((l >> 4) << 2);
#pragma unroll
        for (int r = 0; r < 4; r++) {
            int slot = c0 + row + r;
            if (slot < cnt) {
                int s = slot_token[z * C_ + slot];
                float sc = maxp[b * S_ + s];
                float* orow = out + ((size_t)b * S_ + s) * D_ + n0 + wn * 64 + (l & 15);
#pragma unroll
                for (int n = 0; n < 4; n++)
                    orow[n * 16] = sc * acc[f][n][r];
            }
        }
    }
}

// ============ dropped tokens keep hidden (rare; usually no-op) ============
__global__ __launch_bounds__(256) void combine_dropped(const float* __restrict__ hidden,
                                                       const int* __restrict__ pos,
                                                       const float* __restrict__ maxp,
                                                       float* __restrict__ out) {
    int t = blockIdx.x;
    if (pos[t] < C_) return;
    float sc = maxp[t];
    const float* src = hidden + (size_t)t * D_;
    float* dst = out + (size_t)t * D_;
    for (int d = threadIdx.x; d < D_; d += 256) dst[d] = sc * src[d];
}

extern "C" void kernel_launch(void* const* d_in, const int* in_sizes, int n_in,
                              void* d_out, int out_size, void* d_ws, size_t ws_size,
                              hipStream_t stream) {
    const float* hidden = (const float*)d_in[0];
    const float* gate_w = (const float*)d_in[1];
    const float* w1     = (const float*)d_in[2];
    const float* w2     = (const float*)d_in[3];
    const float* w3     = (const float*)d_in[4];

    float* out        = (float*)d_out;
    float* logits_out = out + (size_t)B_ * S_ * D_;

    char* ws = (char*)d_ws;
    u16* hidden_bf = (u16*)ws;            ws += (size_t)B_ * S_ * D_ * 2;
    u16* w1t       = (u16*)ws;            ws += (size_t)E_ * D_ * FF_ * 2;
    u16* w3t       = (u16*)ws;            ws += (size_t)E_ * D_ * FF_ * 2;
    u16* w2t       = (u16*)ws;            ws += (size_t)E_ * D_ * FF_ * 2;
    u16* hbuf      = (u16*)ws;            ws += (size_t)B_ * E_ * C_ * FF_ * 2;
    int*   sel        = (int*)ws;         ws += (size_t)B_ * S_ * 4;
    int*   pos        = (int*)ws;         ws += (size_t)B_ * S_ * 4;
    float* maxp       = (float*)ws;       ws += (size_t)B_ * S_ * 4;
    int*   slot_token = (int*)ws;         ws += (size_t)B_ * E_ * C_ * 4;
    int*   counts     = (int*)ws;         ws += (size_t)B_ * E_ * 4;

    static bool attr_done = false;
    (void)hipFuncSetAttribute((const void*)gemm1_kernel,
                              hipFuncAttributeMaxDynamicSharedMemorySize, 131072);
    (void)hipFuncSetAttribute((const void*)gemm2_kernel,
                              hipFuncAttributeMaxDynamicSharedMemorySize, 131072);
    (void)attr_done;

    router_kernel<<<B_ * S_ / 4, 256, 0, stream>>>(hidden, gate_w, logits_out, sel, maxp, hidden_bf);
    scan_kernel<<<1, 128, 0, stream>>>(sel, pos, slot_token, counts);

    transpose_cvt<<<dim3(FF_ / 64, D_ / 64, E_), 256, 0, stream>>>(w1, w1t, D_, FF_);
    transpose_cvt<<<dim3(FF_ / 64, D_ / 64, E_), 256, 0, stream>>>(w3, w3t, D_, FF_);
    transpose_cvt<<<dim3(D_ / 64, FF_ / 64, E_), 256, 0, stream>>>(w2, w2t, FF_, D_);

    gemm1_kernel<<<dim3(32, 4, 16), 512, 131072, stream>>>(hidden_bf, w1t, w3t, slot_token, counts, hbuf);
    gemm2_kernel<<<dim3(4, 4, 16), 512, 131072, stream>>>(hbuf, w2t, slot_token, counts, maxp, out);
    combine_dropped<<<B_ * S_, 256, 0, stream>>>(hidden, pos, maxp, out);
}

// Round 4
// 501.237 us; speedup vs baseline: 1.2160x; 1.0321x over previous
//
#include <hip/hip_runtime.h>
#include <hip/hip_bf16.h>
#include <stdint.h>

#define B_  2
#define S_  4096
#define D_  1024
#define FF_ 4096
#define E_  8
#define C_  1024

typedef unsigned short u16;
typedef unsigned int   u32;
typedef float f32x4  __attribute__((ext_vector_type(4)));
typedef short bf16x8 __attribute__((ext_vector_type(8)));
typedef u16   u16x8  __attribute__((ext_vector_type(8)));

static __device__ __forceinline__ u16 f2bf(float f) {
    union { float f; u32 u; } v; v.f = f;
    u32 u = v.u;
    u32 r = (u + 0x7FFFu + ((u >> 16) & 1u)) >> 16;  // RNE; inputs are finite
    return (u16)r;
}

static __device__ __forceinline__ void gload_lds16(const u16* g, u16* l) {
    __builtin_amdgcn_global_load_lds(
        (const __attribute__((address_space(1))) u32*)g,
        (__attribute__((address_space(3))) u32*)l, 16, 0, 0);
}

#define BAR()    asm volatile("s_barrier" ::: "memory")
#define WAITV(n) asm volatile("s_waitcnt vmcnt(" #n ")" ::: "memory")

// ============ transpose + convert: [K][N] fp32 -> [N][K] bf16, per expert ============
__global__ __launch_bounds__(256) void transpose_cvt(const float* __restrict__ src,
                                                     u16* __restrict__ dst, int K, int N) {
    __shared__ u16 t[64 * 64];
    size_t mat = (size_t)blockIdx.z * K * N;
    int n0 = blockIdx.x * 64, k0 = blockIdx.y * 64;
    int l = threadIdx.x & 63, w = threadIdx.x >> 6;
#pragma unroll
    for (int p = 0; p < 2; ++p) {
        int k = p * 32 + w * 8 + ((l >> 4) << 1);     // even k
        int n = (l & 15) * 4;
        float4 v0 = *(const float4*)&src[mat + (size_t)(k0 + k) * N + n0 + n];
        float4 v1 = *(const float4*)&src[mat + (size_t)(k0 + k + 1) * N + n0 + n];
        float a0[4] = {v0.x, v0.y, v0.z, v0.w};
        float a1[4] = {v1.x, v1.y, v1.z, v1.w};
#pragma unroll
        for (int j = 0; j < 4; ++j) {
            int nn = n + j;
            u32 pk = (u32)f2bf(a0[j]) | ((u32)f2bf(a1[j]) << 16);
            int slot = (k >> 3) ^ ((nn & 7) ^ ((nn >> 3) & 7));
            *(u32*)((char*)t + nn * 128 + slot * 16 + (k & 7) * 2) = pk;
        }
    }
    __syncthreads();
#pragma unroll
    for (int p = 0; p < 2; ++p) {
        int n = p * 32 + (threadIdx.x >> 3);
        int k8 = threadIdx.x & 7;
        int slot = k8 ^ ((n & 7) ^ ((n >> 3) & 7));
        u16x8 v = *(u16x8*)((char*)t + n * 128 + slot * 16);
        *(u16x8*)&dst[mat + (size_t)(n0 + n) * K + k0 + k8 * 8] = v;
    }
}

// ============ router: logits (fp64 accum), argmax, max softmax prob; fused bf16 cvt ============
__global__ __launch_bounds__(256) void router_kernel(const float* __restrict__ hidden,
                                                     const float* __restrict__ gate_w,
                                                     float* __restrict__ logits_out,
                                                     int* __restrict__ sel,
                                                     float* __restrict__ maxp,
                                                     u16* __restrict__ xbf) {
    __shared__ float gw[D_ * E_];   // 32 KB
    for (int i = threadIdx.x; i < D_ * E_ / 4; i += 256)
        ((float4*)gw)[i] = ((const float4*)gate_w)[i];
    __syncthreads();

    int wave = threadIdx.x >> 6, lane = threadIdx.x & 63;
    int tok = blockIdx.x * 4 + wave;              // [0, B*S)
    const float* hrow = hidden + (size_t)tok * D_;
    u16* xrow = xbf + (size_t)tok * D_;

    double acc[8] = {0, 0, 0, 0, 0, 0, 0, 0};
#pragma unroll 4
    for (int i = 0; i < D_ / 64; i++) {
        int d = i * 64 + lane;
        float h = hrow[d];
        xrow[d] = f2bf(h);
        const float4* g4 = (const float4*)(gw + d * 8);
        float4 g0 = g4[0], g1 = g4[1];
        acc[0] += (double)h * g0.x; acc[1] += (double)h * g0.y;
        acc[2] += (double)h * g0.z; acc[3] += (double)h * g0.w;
        acc[4] += (double)h * g1.x; acc[5] += (double)h * g1.y;
        acc[6] += (double)h * g1.z; acc[7] += (double)h * g1.w;
    }
#pragma unroll
    for (int off = 32; off > 0; off >>= 1)
#pragma unroll
        for (int e = 0; e < 8; e++)
            acc[e] += __shfl_xor(acc[e], off);

    float l[8];
#pragma unroll
    for (int e = 0; e < 8; e++) l[e] = (float)acc[e];
    if (lane < 8) logits_out[(size_t)tok * 8 + lane] = l[lane];

    int am = 0; float mx = l[0];
#pragma unroll
    for (int e = 1; e < 8; e++) if (l[e] > mx) { mx = l[e]; am = e; }
    float sum = 0.f;
#pragma unroll
    for (int e = 0; e < 8; e++) sum += expf(l[e] - mx);
    if (lane == 0) { sel[tok] = am; maxp[tok] = 1.0f / sum; }
}

// ============ routing scan: per-(batch,expert) rank via wave ballots ============
__global__ void scan_kernel(const int* __restrict__ sel, int* __restrict__ pos,
                            int* __restrict__ slot_token, int* __restrict__ counts) {
    int wave = threadIdx.x >> 6, lane = threadIdx.x & 63;
    int b = wave;
    int carry[8] = {0, 0, 0, 0, 0, 0, 0, 0};
    unsigned long long below = (lane == 0) ? 0ull : ((~0ull) >> (64 - lane));
    for (int s0 = 0; s0 < S_; s0 += 64) {
        int s = s0 + lane;
        int e = sel[b * S_ + s];
        int p = 0;
#pragma unroll
        for (int ex = 0; ex < 8; ex++) {
            unsigned long long m = __ballot(e == ex);
            if (e == ex) p = carry[ex] + (int)__popcll(m & below);
            carry[ex] += (int)__popcll(m);
        }
        pos[b * S_ + s] = p;
        if (p < C_) slot_token[(b * E_ + e) * C_ + p] = s;
    }
    if (lane < 8) {
        int c = carry[lane];
        counts[b * E_ + lane] = c < C_ ? c : C_;
    }
}

// ============ GEMM1: h = silu(x@w1) * (x@w3) ============
// tile 256(M) x 128(N per panel). K-phase=32, 4-slot LDS rotation, prefetch depth 3,
// 8 waves (2M x 4N). Chunk swizzle: 64B rows, 4x16B chunks, phys = kchunk ^ ((row>>1)&3)
// -> ds_read_b128 2-way (free); global_load_lds dest linear, source inverse-permuted.
__global__ __launch_bounds__(512, 2) void gemm1_kernel(const u16* __restrict__ x,
                                                       const u16* __restrict__ w1t,
                                                       const u16* __restrict__ w3t,
                                                       const int* __restrict__ slot_token,
                                                       const int* __restrict__ counts,
                                                       u16* __restrict__ hbuf) {
    extern __shared__ u16 lds[];   // 4 * 16384 u16 = 128 KB
    // bijective XCD chunk swizzle (nwg = 2048, q = 256)
    int phys = blockIdx.x + 32 * (blockIdx.y + 4 * blockIdx.z);
    int virt = (phys & 7) * 256 + (phys >> 3);
    int bx = virt & 31, by = (virt >> 5) & 3, bz = virt >> 7;

    int z = bz;
    int cnt = counts[z];
    int c0 = by * 256;
    if (c0 >= cnt) return;
    int n0 = bx * 128;
    int b = z >> 3, e = z & 7;

    int tid = threadIdx.x, w = tid >> 6, l = tid & 63;
    int wm = w >> 2, wn = w & 3;

    // staging: thread writes phys chunk (tid&3) of row (tid>>2); source k-chunk inverse-swizzled
    int arow0 = tid >> 2, arow1 = arow0 + 128;
    int lk = ((tid & 3) ^ ((tid >> 3) & 3)) * 8;   // (row>>1)&3 identical for row and row+128
    int as0 = c0 + arow0, as1 = c0 + arow1;
    int tok0 = slot_token[z * C_ + (as0 < cnt ? as0 : 0)];
    int tok1 = slot_token[z * C_ + (as1 < cnt ? as1 : 0)];
    const u16* pA0 = x + ((size_t)(b * S_ + tok0)) * D_ + lk;
    const u16* pA1 = x + ((size_t)(b * S_ + tok1)) * D_ + lk;
    const u16* pB1 = w1t + ((size_t)e * FF_ + n0 + arow0) * D_ + lk;
    const u16* pB3 = w3t + ((size_t)e * FF_ + n0 + arow0) * D_ + lk;
    u32 wsl = (u32)w * 512;

    // fragment read offsets (u16 units); chunk XOR collapses to per-lane constant
    u32 ck  = (u32)(((l >> 4) ^ ((l >> 1) & 3)) * 8);
    u32 aoff  = (u32)(wm * 128 + (l & 15)) * 32 + ck;                 // + f*512
    u32 b1off = 8192  + (u32)(wn * 32 + (l & 15)) * 32 + ck;          // + n*512
    u32 b3off = 12288 + (u32)(wn * 32 + (l & 15)) * 32 + ck;

    auto STAGE = [&](int t) {
        u16* Ls = lds + ((t & 3) << 14);
        int ko = t << 5;
        gload_lds16(pA0 + ko, Ls + wsl);
        gload_lds16(pA1 + ko, Ls + 4096 + wsl);
        gload_lds16(pB1 + ko, Ls + 8192 + wsl);
        gload_lds16(pB3 + ko, Ls + 12288 + wsl);
    };

    f32x4 acc1[8][2] = {};
    f32x4 acc3[8][2] = {};

    constexpr int NK = D_ / 32;  // 32
    STAGE(0); STAGE(1); STAGE(2);
    for (int t = 0; t < NK; ++t) {
        if (t + 2 < NK)      { WAITV(8); }
        else if (t + 1 < NK) { WAITV(4); }
        else                 { WAITV(0); }
        BAR();
        if (t + 3 < NK) STAGE(t + 3);
        const u16* Ls = lds + ((t & 3) << 14);
        bf16x8 af[8], b1f[2], b3f[2];
#pragma unroll
        for (int f = 0; f < 8; f++) af[f] = *(const bf16x8*)(Ls + aoff + f * 512);
#pragma unroll
        for (int n = 0; n < 2; n++) {
            b1f[n] = *(const bf16x8*)(Ls + b1off + n * 512);
            b3f[n] = *(const bf16x8*)(Ls + b3off + n * 512);
        }
        __builtin_amdgcn_s_setprio(1);
#pragma unroll
        for (int f = 0; f < 8; f++)
#pragma unroll
            for (int n = 0; n < 2; n++) {
                acc1[f][n] = __builtin_amdgcn_mfma_f32_16x16x32_bf16(af[f], b1f[n], acc1[f][n], 0, 0, 0);
                acc3[f][n] = __builtin_amdgcn_mfma_f32_16x16x32_bf16(af[f], b3f[n], acc3[f][n], 0, 0, 0);
            }
        __builtin_amdgcn_s_setprio(0);
    }

#pragma unroll
    for (int f = 0; f < 8; f++) {
        int row = wm * 128 + f * 16 + ((l >> 4) << 2);
#pragma unroll
        for (int r = 0; r < 4; r++) {
            int slot = c0 + row + r;
            if (slot < cnt) {
                size_t base = ((size_t)z * C_ + slot) * FF_ + n0 + wn * 32 + (l & 15);
#pragma unroll
                for (int n = 0; n < 2; n++) {
                    float g = acc1[f][n][r], uu = acc3[f][n][r];
                    float h = (g / (1.f + __expf(-g))) * uu;
                    hbuf[base + n * 16] = f2bf(h);
                }
            }
        }
    }
}

// ============ GEMM2: out[token] = maxp * (h @ w2), scatter epilogue ============
// tile 256(M) x 256(N). K-phase=32, 4-slot rotation, prefetch depth 3, 8 waves (2M x 4N).
__global__ __launch_bounds__(512, 2) void gemm2_kernel(const u16* __restrict__ hbuf,
                                                       const u16* __restrict__ w2t,
                                                       const int* __restrict__ slot_token,
                                                       const int* __restrict__ counts,
                                                       const float* __restrict__ maxp,
                                                       float* __restrict__ out) {
    extern __shared__ u16 lds[];   // 128 KB
    // bijective XCD chunk swizzle (nwg = 256, q = 32)
    int phys = blockIdx.x + 4 * (blockIdx.y + 4 * blockIdx.z);
    int virt = (phys & 7) * 32 + (phys >> 3);
    int bx = virt & 3, by = (virt >> 2) & 3, bz = virt >> 4;

    int z = bz;
    int cnt = counts[z];
    int c0 = by * 256;
    if (c0 >= cnt) return;
    int n0 = bx * 256;
    int b = z >> 3, e = z & 7;

    int tid = threadIdx.x, w = tid >> 6, l = tid & 63;
    int wm = w >> 2, wn = w & 3;

    int arow0 = tid >> 2;
    int lk = ((tid & 3) ^ ((tid >> 3) & 3)) * 8;
    const u16* pA0 = hbuf + ((size_t)z * C_ + c0 + arow0) * FF_ + lk;
    const u16* pA1 = pA0 + (size_t)128 * FF_;
    const u16* pB0 = w2t + ((size_t)e * D_ + n0 + arow0) * FF_ + lk;
    const u16* pB1 = pB0 + (size_t)128 * FF_;
    u32 wsl = (u32)w * 512;

    u32 ck  = (u32)(((l >> 4) ^ ((l >> 1) & 3)) * 8);
    u32 aoff = (u32)(wm * 128 + (l & 15)) * 32 + ck;                 // + f*512
    u32 boff = 8192 + (u32)(wn * 64 + (l & 15)) * 32 + ck;           // + n*512

    auto STAGE = [&](int t) {
        u16* Ls = lds + ((t & 3) << 14);
        int ko = t << 5;
        gload_lds16(pA0 + ko, Ls + wsl);
        gload_lds16(pA1 + ko, Ls + 4096 + wsl);
        gload_lds16(pB0 + ko, Ls + 8192 + wsl);
        gload_lds16(pB1 + ko, Ls + 12288 + wsl);
    };

    f32x4 acc[8][4] = {};

    constexpr int NK = FF_ / 32;  // 128
    STAGE(0); STAGE(1); STAGE(2);
    for (int t = 0; t < NK; ++t) {
        if (t + 2 < NK)      { WAITV(8); }
        else if (t + 1 < NK) { WAITV(4); }
        else                 { WAITV(0); }
        BAR();
        if (t + 3 < NK) STAGE(t + 3);
        const u16* Ls = lds + ((t & 3) << 14);
        bf16x8 af[8], bfv[4];
#pragma unroll
        for (int f = 0; f < 8; f++) af[f] = *(const bf16x8*)(Ls + aoff + f * 512);
#pragma unroll
        for (int n = 0; n < 4; n++) bfv[n] = *(const bf16x8*)(Ls + boff + n * 512);
        __builtin_amdgcn_s_setprio(1);
#pragma unroll
        for (int f = 0; f < 8; f++)
#pragma unroll
            for (int n = 0; n < 4; n++)
                acc[f][n] = __builtin_amdgcn_mfma_f32_16x16x32_bf16(af[f], bfv[n], acc[f][n], 0, 0, 0);
        __builtin_amdgcn_s_setprio(0);
    }

#pragma unroll
    for (int f = 0; f < 8; f++) {
        int row = wm * 128 + f * 16 + ((l >> 4) << 2);
#pragma unroll
        for (int r = 0; r < 4; r++) {
            int slot = c0 + row + r;
            if (slot < cnt) {
                int s = slot_token[z * C_ + slot];
                float sc = maxp[b * S_ + s];
                float* orow = out + ((size_t)b * S_ + s) * D_ + n0 + wn * 64 + (l & 15);
#pragma unroll
                for (int n = 0; n < 4; n++)
                    orow[n * 16] = sc * acc[f][n][r];
            }
        }
    }
}

// ============ dropped tokens keep hidden (rare; usually no-op) ============
__global__ __launch_bounds__(256) void combine_dropped(const float* __restrict__ hidden,
                                                       const int* __restrict__ pos,
                                                       const float* __restrict__ maxp,
                                                       float* __restrict__ out) {
    int t = blockIdx.x;
    if (pos[t] < C_) return;
    float sc = maxp[t];
    const float* src = hidden + (size_t)t * D_;
    float* dst = out + (size_t)t * D_;
    for (int d = threadIdx.x; d < D_; d += 256) dst[d] = sc * src[d];
}

extern "C" void kernel_launch(void* const* d_in, const int* in_sizes, int n_in,
                              void* d_out, int out_size, void* d_ws, size_t ws_size,
                              hipStream_t stream) {
    const float* hidden = (const float*)d_in[0];
    const float* gate_w = (const float*)d_in[1];
    const float* w1     = (const float*)d_in[2];
    const float* w2     = (const float*)d_in[3];
    const float* w3     = (const float*)d_in[4];

    float* out        = (float*)d_out;
    float* logits_out = out + (size_t)B_ * S_ * D_;

    char* ws = (char*)d_ws;
    u16* hidden_bf = (u16*)ws;            ws += (size_t)B_ * S_ * D_ * 2;
    u16* w1t       = (u16*)ws;            ws += (size_t)E_ * D_ * FF_ * 2;
    u16* w3t       = (u16*)ws;            ws += (size_t)E_ * D_ * FF_ * 2;
    u16* w2t       = (u16*)ws;            ws += (size_t)E_ * D_ * FF_ * 2;
    u16* hbuf      = (u16*)ws;            ws += (size_t)B_ * E_ * C_ * FF_ * 2;
    int*   sel        = (int*)ws;         ws += (size_t)B_ * S_ * 4;
    int*   pos        = (int*)ws;         ws += (size_t)B_ * S_ * 4;
    float* maxp       = (float*)ws;       ws += (size_t)B_ * S_ * 4;
    int*   slot_token = (int*)ws;         ws += (size_t)B_ * E_ * C_ * 4;
    int*   counts     = (int*)ws;         ws += (size_t)B_ * E_ * 4;

    (void)hipFuncSetAttribute((const void*)gemm1_kernel,
                              hipFuncAttributeMaxDynamicSharedMemorySize, 131072);
    (void)hipFuncSetAttribute((const void*)gemm2_kernel,
                              hipFuncAttributeMaxDynamicSharedMemorySize, 131072);

    router_kernel<<<B_ * S_ / 4, 256, 0, stream>>>(hidden, gate_w, logits_out, sel, maxp, hidden_bf);
    scan_kernel<<<1, 128, 0, stream>>>(sel, pos, slot_token, counts);

    transpose_cvt<<<dim3(FF_ / 64, D_ / 64, E_), 256, 0, stream>>>(w1, w1t, D_, FF_);
    transpose_cvt<<<dim3(FF_ / 64, D_ / 64, E_), 256, 0, stream>>>(w3, w3t, D_, FF_);
    transpose_cvt<<<dim3(D_ / 64, FF_ / 64, E_), 256, 0, stream>>>(w2, w2t, FF_, D_);

    gemm1_kernel<<<dim3(32, 4, 16), 512, 131072, stream>>>(hidden_bf, w1t, w3t, slot_token, counts, hbuf);
    gemm2_kernel<<<dim3(4, 4, 16), 512, 131072, stream>>>(hbuf, w2t, slot_token, counts, maxp, out);
    combine_dropped<<<B_ * S_, 256, 0, stream>>>(hidden, pos, maxp, out);
}

// Round 5
// 490.812 us; speedup vs baseline: 1.2418x; 1.0212x over previous
//
#include <hip/hip_runtime.h>
#include <hip/hip_bf16.h>
#include <stdint.h>

#define B_  2
#define S_  4096
#define D_  1024
#define FF_ 4096
#define E_  8
#define C_  1024

typedef unsigned short u16;
typedef unsigned int   u32;
typedef float f32x4  __attribute__((ext_vector_type(4)));
typedef short bf16x8 __attribute__((ext_vector_type(8)));
typedef u16   u16x8  __attribute__((ext_vector_type(8)));

static __device__ __forceinline__ u16 f2bf(float f) {
    union { float f; u32 u; } v; v.f = f;
    u32 u = v.u;
    u32 r = (u + 0x7FFFu + ((u >> 16) & 1u)) >> 16;  // RNE; inputs are finite
    return (u16)r;
}

static __device__ __forceinline__ void gload_lds16(const u16* g, u16* l) {
    __builtin_amdgcn_global_load_lds(
        (const __attribute__((address_space(1))) u32*)g,
        (__attribute__((address_space(3))) u32*)l, 16, 0, 0);
}

#define BAR()    asm volatile("s_barrier" ::: "memory")
#define WAITV(n) asm volatile("s_waitcnt vmcnt(" #n ")" ::: "memory")
#define WAITL0() do { asm volatile("s_waitcnt lgkmcnt(0)" ::: "memory"); \
                      __builtin_amdgcn_sched_barrier(0); } while (0)

// ============ transpose + convert: [K][N] fp32 -> [N][K] bf16, per expert ============
__global__ __launch_bounds__(256) void transpose_cvt(const float* __restrict__ src,
                                                     u16* __restrict__ dst, int K, int N) {
    __shared__ u16 t[64 * 64];
    size_t mat = (size_t)blockIdx.z * K * N;
    int n0 = blockIdx.x * 64, k0 = blockIdx.y * 64;
    int l = threadIdx.x & 63, w = threadIdx.x >> 6;
#pragma unroll
    for (int p = 0; p < 2; ++p) {
        int k = p * 32 + w * 8 + ((l >> 4) << 1);     // even k
        int n = (l & 15) * 4;
        float4 v0 = *(const float4*)&src[mat + (size_t)(k0 + k) * N + n0 + n];
        float4 v1 = *(const float4*)&src[mat + (size_t)(k0 + k + 1) * N + n0 + n];
        float a0[4] = {v0.x, v0.y, v0.z, v0.w};
        float a1[4] = {v1.x, v1.y, v1.z, v1.w};
#pragma unroll
        for (int j = 0; j < 4; ++j) {
            int nn = n + j;
            u32 pk = (u32)f2bf(a0[j]) | ((u32)f2bf(a1[j]) << 16);
            int slot = (k >> 3) ^ ((nn & 7) ^ ((nn >> 3) & 7));
            *(u32*)((char*)t + nn * 128 + slot * 16 + (k & 7) * 2) = pk;
        }
    }
    __syncthreads();
#pragma unroll
    for (int p = 0; p < 2; ++p) {
        int n = p * 32 + (threadIdx.x >> 3);
        int k8 = threadIdx.x & 7;
        int slot = k8 ^ ((n & 7) ^ ((n >> 3) & 7));
        u16x8 v = *(u16x8*)((char*)t + n * 128 + slot * 16);
        *(u16x8*)&dst[mat + (size_t)(n0 + n) * K + k0 + k8 * 8] = v;
    }
}

// ============ router: logits (fp64 accum), argmax, max softmax prob; fused bf16 cvt ============
__global__ __launch_bounds__(256) void router_kernel(const float* __restrict__ hidden,
                                                     const float* __restrict__ gate_w,
                                                     float* __restrict__ logits_out,
                                                     int* __restrict__ sel,
                                                     float* __restrict__ maxp,
                                                     u16* __restrict__ xbf) {
    __shared__ float gw[D_ * E_];   // 32 KB
    for (int i = threadIdx.x; i < D_ * E_ / 4; i += 256)
        ((float4*)gw)[i] = ((const float4*)gate_w)[i];
    __syncthreads();

    int wave = threadIdx.x >> 6, lane = threadIdx.x & 63;
    int tok = blockIdx.x * 4 + wave;              // [0, B*S)
    const float* hrow = hidden + (size_t)tok * D_;
    u16* xrow = xbf + (size_t)tok * D_;

    double acc[8] = {0, 0, 0, 0, 0, 0, 0, 0};
#pragma unroll 4
    for (int i = 0; i < D_ / 64; i++) {
        int d = i * 64 + lane;
        float h = hrow[d];
        xrow[d] = f2bf(h);
        const float4* g4 = (const float4*)(gw + d * 8);
        float4 g0 = g4[0], g1 = g4[1];
        acc[0] += (double)h * g0.x; acc[1] += (double)h * g0.y;
        acc[2] += (double)h * g0.z; acc[3] += (double)h * g0.w;
        acc[4] += (double)h * g1.x; acc[5] += (double)h * g1.y;
        acc[6] += (double)h * g1.z; acc[7] += (double)h * g1.w;
    }
#pragma unroll
    for (int off = 32; off > 0; off >>= 1)
#pragma unroll
        for (int e = 0; e < 8; e++)
            acc[e] += __shfl_xor(acc[e], off);

    float l[8];
#pragma unroll
    for (int e = 0; e < 8; e++) l[e] = (float)acc[e];
    if (lane < 8) logits_out[(size_t)tok * 8 + lane] = l[lane];

    int am = 0; float mx = l[0];
#pragma unroll
    for (int e = 1; e < 8; e++) if (l[e] > mx) { mx = l[e]; am = e; }
    float sum = 0.f;
#pragma unroll
    for (int e = 0; e < 8; e++) sum += expf(l[e] - mx);
    if (lane == 0) { sel[tok] = am; maxp[tok] = 1.0f / sum; }
}

// ============ routing scan: per-(batch,expert) rank via wave ballots ============
__global__ void scan_kernel(const int* __restrict__ sel, int* __restrict__ pos,
                            int* __restrict__ slot_token, int* __restrict__ counts) {
    int wave = threadIdx.x >> 6, lane = threadIdx.x & 63;
    int b = wave;
    int carry[8] = {0, 0, 0, 0, 0, 0, 0, 0};
    unsigned long long below = (lane == 0) ? 0ull : ((~0ull) >> (64 - lane));
    for (int s0 = 0; s0 < S_; s0 += 64) {
        int s = s0 + lane;
        int e = sel[b * S_ + s];
        int p = 0;
#pragma unroll
        for (int ex = 0; ex < 8; ex++) {
            unsigned long long m = __ballot(e == ex);
            if (e == ex) p = carry[ex] + (int)__popcll(m & below);
            carry[ex] += (int)__popcll(m);
        }
        pos[b * S_ + s] = p;
        if (p < C_) slot_token[(b * E_ + e) * C_ + p] = s;
    }
    if (lane < 8) {
        int c = carry[lane];
        counts[b * E_ + lane] = c < C_ ? c : C_;
    }
}

// ============ GEMM1: h = silu(x@w1) * (x@w3) ============
// tile 256(M) x 128(N per panel). K-step=32, 4-slot LDS rotation, prefetch depth 3,
// 8 waves (2M x 4N). m201-style sub-phases: per step, 2x {reads || stage-half ->
// lgkm(0) -> setprio(1) 16 MFMA} with one mid-step barrier. vmcnt never 0 mid-loop.
__global__ __launch_bounds__(512, 2) void gemm1_kernel(const u16* __restrict__ x,
                                                       const u16* __restrict__ w1t,
                                                       const u16* __restrict__ w3t,
                                                       const int* __restrict__ slot_token,
                                                       const int* __restrict__ counts,
                                                       u16* __restrict__ hbuf) {
    extern __shared__ u16 lds[];   // 4 * 16384 u16 = 128 KB
    // bijective XCD chunk swizzle (nwg = 2048, q = 256)
    int phys = blockIdx.x + 32 * (blockIdx.y + 4 * blockIdx.z);
    int virt = (phys & 7) * 256 + (phys >> 3);
    int bx = virt & 31, by = (virt >> 5) & 3, bz = virt >> 7;

    int z = bz;
    int cnt = counts[z];
    int c0 = by * 256;
    if (c0 >= cnt) return;
    int n0 = bx * 128;
    int b = z >> 3, e = z & 7;

    int tid = threadIdx.x, w = tid >> 6, l = tid & 63;
    int wm = w >> 2, wn = w & 3;

    // staging: thread writes phys chunk (tid&3) of row (tid>>2); source k-chunk inverse-swizzled
    int arow0 = tid >> 2, arow1 = arow0 + 128;
    int lk = ((tid & 3) ^ ((tid >> 3) & 3)) * 8;   // (row>>1)&3 identical for row and row+128
    int as0 = c0 + arow0, as1 = c0 + arow1;
    int tok0 = slot_token[z * C_ + (as0 < cnt ? as0 : 0)];
    int tok1 = slot_token[z * C_ + (as1 < cnt ? as1 : 0)];
    const u16* pA0 = x + ((size_t)(b * S_ + tok0)) * D_ + lk;
    const u16* pA1 = x + ((size_t)(b * S_ + tok1)) * D_ + lk;
    const u16* pB1 = w1t + ((size_t)e * FF_ + n0 + arow0) * D_ + lk;
    const u16* pB3 = w3t + ((size_t)e * FF_ + n0 + arow0) * D_ + lk;
    u32 wsl = (u32)w * 512;

    // fragment read offsets (u16 units); chunk XOR collapses to per-lane constant
    u32 ck  = (u32)(((l >> 4) ^ ((l >> 1) & 3)) * 8);
    u32 aoff  = (u32)(wm * 128 + (l & 15)) * 32 + ck;                 // + f*512
    u32 b1off = 8192  + (u32)(wn * 32 + (l & 15)) * 32 + ck;          // + n*512
    u32 b3off = 12288 + (u32)(wn * 32 + (l & 15)) * 32 + ck;

    auto STAGE_A = [&](int t) {
        u16* Ls = lds + ((t & 3) << 14);
        int ko = t << 5;
        gload_lds16(pA0 + ko, Ls + wsl);
        gload_lds16(pA1 + ko, Ls + 4096 + wsl);
    };
    auto STAGE_B = [&](int t) {
        u16* Ls = lds + ((t & 3) << 14);
        int ko = t << 5;
        gload_lds16(pB1 + ko, Ls + 8192 + wsl);
        gload_lds16(pB3 + ko, Ls + 12288 + wsl);
    };

    f32x4 acc1[8][2] = {};
    f32x4 acc3[8][2] = {};

    constexpr int NK = D_ / 32;  // 32
    STAGE_A(0); STAGE_B(0); STAGE_A(1); STAGE_B(1); STAGE_A(2); STAGE_B(2);
    for (int t = 0; t < NK; ++t) {
        if (t + 2 < NK)      { WAITV(8); }
        else if (t + 1 < NK) { WAITV(4); }
        else                 { WAITV(0); }
        BAR();
        const u16* Ls = lds + ((t & 3) << 14);
        // ---- sub-phase 0: af0..3 + all B frags; stage A-half of t+3 ----
        bf16x8 af[8], b1f[2], b3f[2];
#pragma unroll
        for (int f = 0; f < 4; f++) af[f] = *(const bf16x8*)(Ls + aoff + f * 512);
#pragma unroll
        for (int n = 0; n < 2; n++) {
            b1f[n] = *(const bf16x8*)(Ls + b1off + n * 512);
            b3f[n] = *(const bf16x8*)(Ls + b3off + n * 512);
        }
        if (t + 3 < NK) STAGE_A(t + 3);
        WAITL0();
        __builtin_amdgcn_s_setprio(1);
#pragma unroll
        for (int f = 0; f < 4; f++)
#pragma unroll
            for (int n = 0; n < 2; n++) {
                acc1[f][n] = __builtin_amdgcn_mfma_f32_16x16x32_bf16(af[f], b1f[n], acc1[f][n], 0, 0, 0);
                acc3[f][n] = __builtin_amdgcn_mfma_f32_16x16x32_bf16(af[f], b3f[n], acc3[f][n], 0, 0, 0);
            }
        __builtin_amdgcn_s_setprio(0);
        BAR();
        // ---- sub-phase 1: af4..7; stage B-half of t+3 ----
#pragma unroll
        for (int f = 4; f < 8; f++) af[f] = *(const bf16x8*)(Ls + aoff + f * 512);
        if (t + 3 < NK) STAGE_B(t + 3);
        WAITL0();
        __builtin_amdgcn_s_setprio(1);
#pragma unroll
        for (int f = 4; f < 8; f++)
#pragma unroll
            for (int n = 0; n < 2; n++) {
                acc1[f][n] = __builtin_amdgcn_mfma_f32_16x16x32_bf16(af[f], b1f[n], acc1[f][n], 0, 0, 0);
                acc3[f][n] = __builtin_amdgcn_mfma_f32_16x16x32_bf16(af[f], b3f[n], acc3[f][n], 0, 0, 0);
            }
        __builtin_amdgcn_s_setprio(0);
    }

#pragma unroll
    for (int f = 0; f < 8; f++) {
        int row = wm * 128 + f * 16 + ((l >> 4) << 2);
#pragma unroll
        for (int r = 0; r < 4; r++) {
            int slot = c0 + row + r;
            if (slot < cnt) {
                size_t base = ((size_t)z * C_ + slot) * FF_ + n0 + wn * 32 + (l & 15);
#pragma unroll
                for (int n = 0; n < 2; n++) {
                    float g = acc1[f][n][r], uu = acc3[f][n][r];
                    float h = (g / (1.f + __expf(-g))) * uu;
                    hbuf[base + n * 16] = f2bf(h);
                }
            }
        }
    }
}

// ============ GEMM2: out[token] = maxp * (h @ w2), scatter epilogue ============
// tile 256(M) x 256(N). K-step=32, 4-slot rotation, depth 3, 8 waves (2M x 4N),
// same m201-style 2-sub-phase schedule.
__global__ __launch_bounds__(512, 2) void gemm2_kernel(const u16* __restrict__ hbuf,
                                                       const u16* __restrict__ w2t,
                                                       const int* __restrict__ slot_token,
                                                       const int* __restrict__ counts,
                                                       const float* __restrict__ maxp,
                                                       float* __restrict__ out) {
    extern __shared__ u16 lds[];   // 128 KB
    // bijective XCD chunk swizzle (nwg = 256, q = 32)
    int phys = blockIdx.x + 4 * (blockIdx.y + 4 * blockIdx.z);
    int virt = (phys & 7) * 32 + (phys >> 3);
    int bx = virt & 3, by = (virt >> 2) & 3, bz = virt >> 4;

    int z = bz;
    int cnt = counts[z];
    int c0 = by * 256;
    if (c0 >= cnt) return;
    int n0 = bx * 256;
    int b = z >> 3, e = z & 7;

    int tid = threadIdx.x, w = tid >> 6, l = tid & 63;
    int wm = w >> 2, wn = w & 3;

    int arow0 = tid >> 2;
    int lk = ((tid & 3) ^ ((tid >> 3) & 3)) * 8;
    const u16* pA0 = hbuf + ((size_t)z * C_ + c0 + arow0) * FF_ + lk;
    const u16* pA1 = pA0 + (size_t)128 * FF_;
    const u16* pB0 = w2t + ((size_t)e * D_ + n0 + arow0) * FF_ + lk;
    const u16* pB1 = pB0 + (size_t)128 * FF_;
    u32 wsl = (u32)w * 512;

    u32 ck  = (u32)(((l >> 4) ^ ((l >> 1) & 3)) * 8);
    u32 aoff = (u32)(wm * 128 + (l & 15)) * 32 + ck;                 // + f*512
    u32 boff = 8192 + (u32)(wn * 64 + (l & 15)) * 32 + ck;           // + n*512

    auto STAGE_A = [&](int t) {
        u16* Ls = lds + ((t & 3) << 14);
        int ko = t << 5;
        gload_lds16(pA0 + ko, Ls + wsl);
        gload_lds16(pA1 + ko, Ls + 4096 + wsl);
    };
    auto STAGE_B = [&](int t) {
        u16* Ls = lds + ((t & 3) << 14);
        int ko = t << 5;
        gload_lds16(pB0 + ko, Ls + 8192 + wsl);
        gload_lds16(pB1 + ko, Ls + 12288 + wsl);
    };

    f32x4 acc[8][4] = {};

    constexpr int NK = FF_ / 32;  // 128
    STAGE_A(0); STAGE_B(0); STAGE_A(1); STAGE_B(1); STAGE_A(2); STAGE_B(2);
    for (int t = 0; t < NK; ++t) {
        if (t + 2 < NK)      { WAITV(8); }
        else if (t + 1 < NK) { WAITV(4); }
        else                 { WAITV(0); }
        BAR();
        const u16* Ls = lds + ((t & 3) << 14);
        // ---- sub-phase 0: af0..3 + bfv0..3; stage A-half ----
        bf16x8 af[8], bfv[4];
#pragma unroll
        for (int f = 0; f < 4; f++) af[f] = *(const bf16x8*)(Ls + aoff + f * 512);
#pragma unroll
        for (int n = 0; n < 4; n++) bfv[n] = *(const bf16x8*)(Ls + boff + n * 512);
        if (t + 3 < NK) STAGE_A(t + 3);
        WAITL0();
        __builtin_amdgcn_s_setprio(1);
#pragma unroll
        for (int f = 0; f < 4; f++)
#pragma unroll
            for (int n = 0; n < 4; n++)
                acc[f][n] = __builtin_amdgcn_mfma_f32_16x16x32_bf16(af[f], bfv[n], acc[f][n], 0, 0, 0);
        __builtin_amdgcn_s_setprio(0);
        BAR();
        // ---- sub-phase 1: af4..7; stage B-half ----
#pragma unroll
        for (int f = 4; f < 8; f++) af[f] = *(const bf16x8*)(Ls + aoff + f * 512);
        if (t + 3 < NK) STAGE_B(t + 3);
        WAITL0();
        __builtin_amdgcn_s_setprio(1);
#pragma unroll
        for (int f = 4; f < 8; f++)
#pragma unroll
            for (int n = 0; n < 4; n++)
                acc[f][n] = __builtin_amdgcn_mfma_f32_16x16x32_bf16(af[f], bfv[n], acc[f][n], 0, 0, 0);
        __builtin_amdgcn_s_setprio(0);
    }

#pragma unroll
    for (int f = 0; f < 8; f++) {
        int row = wm * 128 + f * 16 + ((l >> 4) << 2);
#pragma unroll
        for (int r = 0; r < 4; r++) {
            int slot = c0 + row + r;
            if (slot < cnt) {
                int s = slot_token[z * C_ + slot];
                float sc = maxp[b * S_ + s];
                float* orow = out + ((size_t)b * S_ + s) * D_ + n0 + wn * 64 + (l & 15);
#pragma unroll
                for (int n = 0; n < 4; n++)
                    orow[n * 16] = sc * acc[f][n][r];
            }
        }
    }
}

// ============ dropped tokens keep hidden (rare; usually no-op) ============
__global__ __launch_bounds__(256) void combine_dropped(const float* __restrict__ hidden,
                                                       const int* __restrict__ pos,
                                                       const float* __restrict__ maxp,
                                                       float* __restrict__ out) {
    int t = blockIdx.x;
    if (pos[t] < C_) return;
    float sc = maxp[t];
    const float* src = hidden + (size_t)t * D_;
    float* dst = out + (size_t)t * D_;
    for (int d = threadIdx.x; d < D_; d += 256) dst[d] = sc * src[d];
}

extern "C" void kernel_launch(void* const* d_in, const int* in_sizes, int n_in,
                              void* d_out, int out_size, void* d_ws, size_t ws_size,
                              hipStream_t stream) {
    const float* hidden = (const float*)d_in[0];
    const float* gate_w = (const float*)d_in[1];
    const float* w1     = (const float*)d_in[2];
    const float* w2     = (const float*)d_in[3];
    const float* w3     = (const float*)d_in[4];

    float* out        = (float*)d_out;
    float* logits_out = out + (size_t)B_ * S_ * D_;

    char* ws = (char*)d_ws;
    u16* hidden_bf = (u16*)ws;            ws += (size_t)B_ * S_ * D_ * 2;
    u16* w1t       = (u16*)ws;            ws += (size_t)E_ * D_ * FF_ * 2;
    u16* w3t       = (u16*)ws;            ws += (size_t)E_ * D_ * FF_ * 2;
    u16* w2t       = (u16*)ws;            ws += (size_t)E_ * D_ * FF_ * 2;
    u16* hbuf      = (u16*)ws;            ws += (size_t)B_ * E_ * C_ * FF_ * 2;
    int*   sel        = (int*)ws;         ws += (size_t)B_ * S_ * 4;
    int*   pos        = (int*)ws;         ws += (size_t)B_ * S_ * 4;
    float* maxp       = (float*)ws;       ws += (size_t)B_ * S_ * 4;
    int*   slot_token = (int*)ws;         ws += (size_t)B_ * E_ * C_ * 4;
    int*   counts     = (int*)ws;         ws += (size_t)B_ * E_ * 4;

    (void)hipFuncSetAttribute((const void*)gemm1_kernel,
                              hipFuncAttributeMaxDynamicSharedMemorySize, 131072);
    (void)hipFuncSetAttribute((const void*)gemm2_kernel,
                              hipFuncAttributeMaxDynamicSharedMemorySize, 131072);

    router_kernel<<<B_ * S_ / 4, 256, 0, stream>>>(hidden, gate_w, logits_out, sel, maxp, hidden_bf);
    scan_kernel<<<1, 128, 0, stream>>>(sel, pos, slot_token, counts);

    transpose_cvt<<<dim3(FF_ / 64, D_ / 64, E_), 256, 0, stream>>>(w1, w1t, D_, FF_);
    transpose_cvt<<<dim3(FF_ / 64, D_ / 64, E_), 256, 0, stream>>>(w3, w3t, D_, FF_);
    transpose_cvt<<<dim3(D_ / 64, FF_ / 64, E_), 256, 0, stream>>>(w2, w2t, FF_, D_);

    gemm1_kernel<<<dim3(32, 4, 16), 512, 131072, stream>>>(hidden_bf, w1t, w3t, slot_token, counts, hbuf);
    gemm2_kernel<<<dim3(4, 4, 16), 512, 131072, stream>>>(hbuf, w2t, slot_token, counts, maxp, out);
    combine_dropped<<<B_ * S_, 256, 0, stream>>>(hidden, pos, maxp, out);
}